// Round 1
// baseline (139.906 us; speedup 1.0000x reference)
//
#include <hip/hip_runtime.h>

#define D_ATT 256
#define DG 32
#define NG 8
#define NB 4
#define LL 512
#define M_ROWS (NB * LL)   // 2048

// ---------------------------------------------------------------------------
// Kernel 1: Y[mat][m][n] = sum_k X[m][k] * W_mat[n][k]   (y = x @ W.T)
// grid (12, 32): bx -> 64-wide n-tile over 3*256 cols, by -> 64-row m-tile
// ---------------------------------------------------------------------------
__global__ __launch_bounds__(256) void qkv_gemm(
    const float* __restrict__ X, const float* __restrict__ Wq,
    const float* __restrict__ Wk, const float* __restrict__ Wv,
    float* __restrict__ Y)
{
    const int bx = blockIdx.x;           // 0..11
    const int by = blockIdx.y;           // 0..31
    const int mat = bx >> 2;             // 0..2
    const int n0 = (bx & 3) * 64;        // col within matrix
    const int m0 = by * 64;
    const float* W = (mat == 0) ? Wq : (mat == 1 ? Wk : Wv);

    __shared__ float As[16][68];         // [k][m], pad 68 keeps b128 align + banks
    __shared__ float Bs[16][68];         // [k][n]

    const int t  = threadIdx.x;
    const int tx = t & 15;               // n micro-tile
    const int ty = t >> 4;               // m micro-tile
    const int sm  = t >> 2;              // staging row 0..63
    const int sk4 = t & 3;               // staging float4 col 0..3

    float c[4][4] = {};

    for (int kc = 0; kc < 256; kc += 16) {
        const float4 xa = *(const float4*)(X + (size_t)(m0 + sm) * 256 + kc + sk4 * 4);
        const float4 wb = *(const float4*)(W + (size_t)(n0 + sm) * 256 + kc + sk4 * 4);
        __syncthreads();
        As[sk4 * 4 + 0][sm] = xa.x; As[sk4 * 4 + 1][sm] = xa.y;
        As[sk4 * 4 + 2][sm] = xa.z; As[sk4 * 4 + 3][sm] = xa.w;
        Bs[sk4 * 4 + 0][sm] = wb.x; Bs[sk4 * 4 + 1][sm] = wb.y;
        Bs[sk4 * 4 + 2][sm] = wb.z; Bs[sk4 * 4 + 3][sm] = wb.w;
        __syncthreads();
#pragma unroll
        for (int kk = 0; kk < 16; ++kk) {
            const float4 a = *(const float4*)&As[kk][ty * 4];
            const float4 b = *(const float4*)&Bs[kk][tx * 4];
            const float am[4] = {a.x, a.y, a.z, a.w};
            const float bn[4] = {b.x, b.y, b.z, b.w};
#pragma unroll
            for (int i = 0; i < 4; ++i)
#pragma unroll
                for (int j = 0; j < 4; ++j)
                    c[i][j] = fmaf(am[i], bn[j], c[i][j]);
        }
    }

    float* Yb = Y + (size_t)mat * M_ROWS * 256;
#pragma unroll
    for (int i = 0; i < 4; ++i) {
        const int row = m0 + ty * 4 + i;
        float4 v = make_float4(c[i][0], c[i][1], c[i][2], c[i][3]);
        *(float4*)(Yb + (size_t)row * 256 + n0 + tx * 4) = v;
    }
}

// ---------------------------------------------------------------------------
// Kernel 2: fused grouped-MLP attention, flash-style online softmax.
// grid 512 = 4 batches x 128 q-tiles (TQ=4). block 256.
// thread -> g = t&7, q = (t>>3)&3, phase p = t>>5 (k ≡ p mod 8)
// ---------------------------------------------------------------------------
#define TQ 4
#define KT 16
#define CH 36                  // padded 32-float chunk (144B, 16B aligned)
#define KROW (NG * CH)         // 288 floats per k-row in LDS

__global__ __launch_bounds__(256) void attn_fused(
    const float* __restrict__ Y,
    const float* __restrict__ w_mlp, const float* __restrict__ b_mlp,
    float* __restrict__ out)
{
    const int bid = blockIdx.x;          // 0..511
    const int b   = bid & 3;             // batch -> same-b blocks share XCD pair
    const int q0  = (bid >> 2) * TQ;

    const float* Qm = Y;
    const float* Km = Y + (size_t)M_ROWS * 256;
    const float* Vm = Y + (size_t)2 * M_ROWS * 256;

    const int t = threadIdx.x;
    const int g = t & 7;
    const int q = (t >> 3) & 3;
    const int p = t >> 5;                // 0..7

    __shared__ float Ks[KT * KROW];      // 18 KB
    __shared__ float Vs[KT * KROW];      // 18 KB, transposed: [k][g][d]
    __shared__ float mlA[32][8];         // m per (pair, phase)
    __shared__ float mlB[32][8];         // l per (pair, phase)
    __shared__ float outb[32 * 33];      // combined output, pad 33

    // w_mlp and bias into registers
    float wreg[DG];
#pragma unroll
    for (int d4 = 0; d4 < 8; ++d4) {
        const float4 wv = *(const float4*)(w_mlp + d4 * 4);
        wreg[d4 * 4 + 0] = wv.x; wreg[d4 * 4 + 1] = wv.y;
        wreg[d4 * 4 + 2] = wv.z; wreg[d4 * 4 + 3] = wv.w;
    }
    const float bias = b_mlp[0];

    // Q chunk for (q, g) into registers
    float qr[DG];
    {
        const float* qptr = Qm + ((size_t)(b * LL) + q0 + q) * 256 + g * DG;
#pragma unroll
        for (int d4 = 0; d4 < 8; ++d4) {
            const float4 qv = *(const float4*)(qptr + d4 * 4);
            qr[d4 * 4 + 0] = qv.x; qr[d4 * 4 + 1] = qv.y;
            qr[d4 * 4 + 2] = qv.z; qr[d4 * 4 + 3] = qv.w;
        }
    }

    float m = 0.f, l = 0.f;              // scores >= 0, so m=0 init is safe
    float acc[DG] = {};

    const int sr  = t >> 4;              // staging row 0..15
    const int sc4 = t & 15;              // staging float4 col base

    for (int kt = 0; kt < LL / KT; ++kt) {
        const int k0 = kt * KT;
        __syncthreads();
#pragma unroll
        for (int j = 0; j < 4; ++j) {
            const int c4 = sc4 + 16 * j;                 // 0..63
            const size_t grow = ((size_t)(b * LL) + k0 + sr) * 256 + c4 * 4;
            const float4 kv = *(const float4*)(Km + grow);
            *(float4*)&Ks[sr * KROW + (c4 >> 3) * CH + (c4 & 7) * 4] = kv;
            const float4 vv = *(const float4*)(Vm + grow);
            const int c = c4 * 4;
            Vs[sr * KROW + ((c + 0) & 7) * CH + ((c + 0) >> 3)] = vv.x;
            Vs[sr * KROW + ((c + 1) & 7) * CH + ((c + 1) >> 3)] = vv.y;
            Vs[sr * KROW + ((c + 2) & 7) * CH + ((c + 2) >> 3)] = vv.z;
            Vs[sr * KROW + ((c + 3) & 7) * CH + ((c + 3) >> 3)] = vv.w;
        }
        __syncthreads();

#pragma unroll
        for (int half = 0; half < 2; ++half) {
            const int kk = p + half * 8;
            const float* kbase = &Ks[kk * KROW + g * CH];
            float s = bias;
#pragma unroll
            for (int d4 = 0; d4 < 8; ++d4) {
                const float4 kv = *(const float4*)(kbase + d4 * 4);
                s = fmaf(wreg[d4 * 4 + 0], fmaxf(qr[d4 * 4 + 0] - kv.x, 0.f), s);
                s = fmaf(wreg[d4 * 4 + 1], fmaxf(qr[d4 * 4 + 1] - kv.y, 0.f), s);
                s = fmaf(wreg[d4 * 4 + 2], fmaxf(qr[d4 * 4 + 2] - kv.z, 0.f), s);
                s = fmaf(wreg[d4 * 4 + 3], fmaxf(qr[d4 * 4 + 3] - kv.w, 0.f), s);
            }
            s = fmaxf(s, 0.f);
            const float mn = fmaxf(m, s);
            const float alpha = __expf(m - mn);
            const float pv = __expf(s - mn);
            m = mn;
            l = fmaf(l, alpha, pv);
            const float* vbase = &Vs[kk * KROW + g * CH];
#pragma unroll
            for (int d4 = 0; d4 < 8; ++d4) {
                const float4 vv = *(const float4*)(vbase + d4 * 4);
                acc[d4 * 4 + 0] = fmaf(acc[d4 * 4 + 0], alpha, pv * vv.x);
                acc[d4 * 4 + 1] = fmaf(acc[d4 * 4 + 1], alpha, pv * vv.y);
                acc[d4 * 4 + 2] = fmaf(acc[d4 * 4 + 2], alpha, pv * vv.z);
                acc[d4 * 4 + 3] = fmaf(acc[d4 * 4 + 3], alpha, pv * vv.w);
            }
        }
    }

    // ---- combine 8 phases per (q,g) pair ----
    const int pair = q * 8 + g;
    mlA[pair][p] = m;
    mlB[pair][p] = l;
    __syncthreads();

    float M = mlA[pair][0];
#pragma unroll
    for (int j = 1; j < 8; ++j) M = fmaxf(M, mlA[pair][j]);
    float Lt = 0.f;
#pragma unroll
    for (int j = 0; j < 8; ++j) Lt += mlB[pair][j] * __expf(mlA[pair][j] - M);
    const float scale = __expf(m - M) / Lt;

    for (int step = 0; step < 8; ++step) {
        if (p == step) {
            if (step == 0) {
#pragma unroll
                for (int d = 0; d < DG; ++d) outb[pair * 33 + d] = acc[d] * scale;
            } else {
#pragma unroll
                for (int d = 0; d < DG; ++d) outb[pair * 33 + d] += acc[d] * scale;
            }
        }
        __syncthreads();
    }

    // ---- coalesced output write: out[b, q0+qw, d*8+g] ----
    const int qw = t >> 6;               // 0..3 (one q per wave)
    const int cb = t & 63;
#pragma unroll
    for (int rep = 0; rep < 4; ++rep) {
        const int cc = cb + rep * 64;    // 0..255
        const int d = cc >> 3, gg = cc & 7;
        out[((size_t)(b * LL) + q0 + qw) * 256 + cc] = outb[(qw * 8 + gg) * 33 + d];
    }
}

// ---------------------------------------------------------------------------
extern "C" void kernel_launch(void* const* d_in, const int* in_sizes, int n_in,
                              void* d_out, int out_size, void* d_ws, size_t ws_size,
                              hipStream_t stream) {
    (void)in_sizes; (void)n_in; (void)out_size; (void)ws_size;
    const float* x     = (const float*)d_in[0];
    const float* Wq    = (const float*)d_in[1];
    const float* Wk    = (const float*)d_in[2];
    const float* Wv    = (const float*)d_in[3];
    const float* w_mlp = (const float*)d_in[4];
    const float* b_mlp = (const float*)d_in[5];
    float* outp = (float*)d_out;
    float* Y    = (float*)d_ws;          // Q | K | V : 3 * 2048*256 fp32 = 6 MB

    qkv_gemm<<<dim3(12, 32), 256, 0, stream>>>(x, Wq, Wk, Wv, Y);
    attn_fused<<<dim3(512), 256, 0, stream>>>(Y, w_mlp, b_mlp, outp);
}

// Round 2
// 130.230 us; speedup vs baseline: 1.0743x; 1.0743x over previous
//
#include <hip/hip_runtime.h>

typedef float f32x2 __attribute__((ext_vector_type(2)));
typedef float f32x4 __attribute__((ext_vector_type(4)));

#define LL 512
#define M_ROWS 2048            // 4 * 512

__device__ __forceinline__ float quad_swap1(float x) {   // lane ^ 1 within quad
    return __int_as_float(__builtin_amdgcn_mov_dpp(__float_as_int(x), 0xB1, 0xF, 0xF, true));
}
__device__ __forceinline__ float quad_swap2(float x) {   // lane ^ 2 within quad
    return __int_as_float(__builtin_amdgcn_mov_dpp(__float_as_int(x), 0x4E, 0xF, 0xF, true));
}

// ---------------------------------------------------------------------------
// Kernel 1: Y[mat][m][n] = sum_k X[m][k] * W_mat[n][k]  (y = x @ W.T)
// mat==2 writes Vt directly: Vt[m][g*32+d] = V[m][d*8+g] via permuted W rows.
// grid (12, 64): 32m x 64n tiles, 128 threads, kc=32 double-buffered.
// ---------------------------------------------------------------------------
__global__ __launch_bounds__(128) void qkv_gemm(
    const float* __restrict__ X, const float* __restrict__ Wq,
    const float* __restrict__ Wk, const float* __restrict__ Wv,
    float* __restrict__ Y)
{
    const int bx = blockIdx.x;           // 0..11
    const int by = blockIdx.y;           // 0..63
    const int mat = bx >> 2;
    const int n0 = (bx & 3) * 64;
    const int m0 = by * 32;
    const float* W = (mat == 0) ? Wq : (mat == 1 ? Wk : Wv);

    __shared__ float As[2][32][36];      // [k][m], 144B rows (16B aligned)
    __shared__ float Bs[2][32][68];      // [k][n], 272B rows (16B aligned)

    const int t = threadIdx.x;
    const int tx = t & 15;               // n micro
    const int ty = t >> 4;               // m micro (0..7)

    int am[2], ak4[2];
#pragma unroll
    for (int r = 0; r < 2; ++r) { int idx = t + 128 * r; am[r] = idx >> 3; ak4[r] = idx & 7; }
    int bn[4], bk4[4]; size_t brow[4];
#pragma unroll
    for (int r = 0; r < 4; ++r) {
        int idx = t + 128 * r; bn[r] = idx >> 3; bk4[r] = idx & 7;
        int rowc = n0 + bn[r];
        brow[r] = (mat == 2) ? (size_t)(((rowc & 31) << 3) | (rowc >> 5)) : (size_t)rowc;
    }

    f32x4 arg[2], brg[4];
    auto load_tile = [&](int kc) {
#pragma unroll
        for (int r = 0; r < 2; ++r)
            arg[r] = *(const f32x4*)(X + (size_t)(m0 + am[r]) * 256 + kc + ak4[r] * 4);
#pragma unroll
        for (int r = 0; r < 4; ++r)
            brg[r] = *(const f32x4*)(W + brow[r] * 256 + kc + bk4[r] * 4);
    };
    auto store_tile = [&](int buf) {
#pragma unroll
        for (int r = 0; r < 2; ++r)
#pragma unroll
            for (int j = 0; j < 4; ++j) As[buf][ak4[r] * 4 + j][am[r]] = arg[r][j];
#pragma unroll
        for (int r = 0; r < 4; ++r)
#pragma unroll
            for (int j = 0; j < 4; ++j) Bs[buf][bk4[r] * 4 + j][bn[r]] = brg[r][j];
    };

    load_tile(0);
    store_tile(0);
    __syncthreads();

    f32x2 c[4][2];
#pragma unroll
    for (int i = 0; i < 4; ++i) { c[i][0] = (f32x2){0.f, 0.f}; c[i][1] = (f32x2){0.f, 0.f}; }

    for (int it = 0; it < 8; ++it) {
        const int buf = it & 1;
        if (it < 7) load_tile((it + 1) * 32);
#pragma unroll
        for (int kk = 0; kk < 32; ++kk) {
            const f32x4 a4 = *(const f32x4*)&As[buf][kk][ty * 4];
            const f32x4 b4 = *(const f32x4*)&Bs[buf][kk][tx * 4];
            const f32x2 bl = __builtin_shufflevector(b4, b4, 0, 1);
            const f32x2 bh = __builtin_shufflevector(b4, b4, 2, 3);
#pragma unroll
            for (int i = 0; i < 4; ++i) {
                const f32x2 ai = {a4[i], a4[i]};
                c[i][0] += ai * bl;
                c[i][1] += ai * bh;
            }
        }
        if (it < 7) {
            __syncthreads();
            store_tile(buf ^ 1);
            __syncthreads();
        }
    }

    float* Yb = Y + (size_t)mat * M_ROWS * 256;
#pragma unroll
    for (int i = 0; i < 4; ++i) {
        f32x4 v = {c[i][0].x, c[i][0].y, c[i][1].x, c[i][1].y};
        *(f32x4*)(Yb + (size_t)(m0 + ty * 4 + i) * 256 + n0 + tx * 4) = v;
    }
}

// ---------------------------------------------------------------------------
// Kernel 2: fused grouped-MLP attention. No LDS in the main loop.
// grid 256 = 4 batches x 64 q-tiles (8 q-rows each), 512 threads.
// thread = (p = t>>5: k-phase 0..15, g = (t>>2)&7, dh = t&3: d-quarter).
// Each thread: all 8 q in regs, 8 d's of K/V read from global (L2-hot),
// quad DPP combine for scores, no-max online softmax (scores are bounded).
// ---------------------------------------------------------------------------
__global__ __launch_bounds__(512, 2) void attn_fused(
    const float* __restrict__ Y,
    const float* __restrict__ w_mlp, const float* __restrict__ b_mlp,
    float* __restrict__ out)
{
    const float* Qm = Y;
    const float* Km = Y + (size_t)M_ROWS * 256;
    const float* Vt = Y + (size_t)2 * M_ROWS * 256;

    const int bid = blockIdx.x;          // 0..255
    const int b = bid & 3;               // batch -> XCD pair keeps K/V L2-hot
    const int q0 = (bid >> 2) * 8;

    const int t = threadIdx.x;
    const int dh = t & 3;                // d-quarter (8 floats)
    const int g = (t >> 2) & 7;
    const int p = t >> 5;                // k-phase 0..15
    const int lane32 = t & 31;           // g*4+dh

    __shared__ float accbuf[16][32][20]; // 40 KB: [p][g*4+dh][2q*8 + l at 16,17]

    const int doff = g * 32 + dh * 8;
    const float bias = b_mlp[0];

    f32x2 w2[4];
    {
        f32x4 wa = *(const f32x4*)(w_mlp + dh * 8);
        f32x4 wb = *(const f32x4*)(w_mlp + dh * 8 + 4);
        w2[0] = __builtin_shufflevector(wa, wa, 0, 1);
        w2[1] = __builtin_shufflevector(wa, wa, 2, 3);
        w2[2] = __builtin_shufflevector(wb, wb, 0, 1);
        w2[3] = __builtin_shufflevector(wb, wb, 2, 3);
    }

    f32x2 qr2[8][4];
#pragma unroll
    for (int q = 0; q < 8; ++q) {
        const float* qp = Qm + ((size_t)(b * LL) + q0 + q) * 256 + doff;
        f32x4 qa = *(const f32x4*)qp;
        f32x4 qb = *(const f32x4*)(qp + 4);
        qr2[q][0] = __builtin_shufflevector(qa, qa, 0, 1);
        qr2[q][1] = __builtin_shufflevector(qa, qa, 2, 3);
        qr2[q][2] = __builtin_shufflevector(qb, qb, 0, 1);
        qr2[q][3] = __builtin_shufflevector(qb, qb, 2, 3);
    }

    f32x2 acc2[8][4];
#pragma unroll
    for (int q = 0; q < 8; ++q)
#pragma unroll
        for (int j = 0; j < 4; ++j) acc2[q][j] = (f32x2){0.f, 0.f};
    float l[8] = {0.f, 0.f, 0.f, 0.f, 0.f, 0.f, 0.f, 0.f};

    const float* kptr = Km + ((size_t)(b * LL) + p) * 256 + doff;
    const float* vptr = Vt + ((size_t)(b * LL) + p) * 256 + doff;

    auto compute = [&](f32x4 ka, f32x4 kb, f32x4 va, f32x4 vb) {
        f32x2 k2[4] = {__builtin_shufflevector(ka, ka, 0, 1),
                       __builtin_shufflevector(ka, ka, 2, 3),
                       __builtin_shufflevector(kb, kb, 0, 1),
                       __builtin_shufflevector(kb, kb, 2, 3)};
        f32x2 v2[4] = {__builtin_shufflevector(va, va, 0, 1),
                       __builtin_shufflevector(va, va, 2, 3),
                       __builtin_shufflevector(vb, vb, 0, 1),
                       __builtin_shufflevector(vb, vb, 2, 3)};
        const f32x2 z2 = {0.f, 0.f};
#pragma unroll
        for (int q = 0; q < 8; ++q) {
            f32x2 s2 = z2;
#pragma unroll
            for (int j = 0; j < 4; ++j) {
                f32x2 d2 = qr2[q][j] - k2[j];
                f32x2 r2 = __builtin_elementwise_max(d2, z2);
                s2 += w2[j] * r2;
            }
            float s = s2.x + s2.y;
            s += quad_swap1(s);              // + partner d-quarter
            s += quad_swap2(s);              // full 32-d sum across quad
            s = fmaxf(s + bias, 0.f);
            const float e = __expf(s);       // s in [0, ~few]: no max needed
            l[q] += e;
            const f32x2 e2 = {e, e};
#pragma unroll
            for (int j = 0; j < 4; ++j) acc2[q][j] += e2 * v2[j];
        }
    };

    f32x4 ka = *(const f32x4*)kptr, kb = *(const f32x4*)(kptr + 4);
    f32x4 va = *(const f32x4*)vptr, vb = *(const f32x4*)(vptr + 4);
#pragma unroll 1
    for (int i = 0; i < 31; ++i) {
        kptr += 16 * 256; vptr += 16 * 256;
        f32x4 ka2 = *(const f32x4*)kptr, kb2 = *(const f32x4*)(kptr + 4);
        f32x4 va2 = *(const f32x4*)vptr, vb2 = *(const f32x4*)(vptr + 4);
        compute(ka, kb, va, vb);
        ka = ka2; kb = kb2; va = va2; vb = vb2;
    }
    compute(ka, kb, va, vb);

    // ---- epilogue: reduce over the 16 k-phases via LDS, 4 rounds of 2 q ----
#pragma unroll 1
    for (int r = 0; r < 4; ++r) {
#pragma unroll
        for (int qq = 0; qq < 2; ++qq) {
            const int q = r * 2 + qq;
#pragma unroll
            for (int j = 0; j < 4; ++j)
                *(f32x2*)&accbuf[p][lane32][qq * 8 + j * 2] = acc2[q][j];
        }
        if (dh == 0) {
            accbuf[p][lane32][16] = l[r * 2];
            accbuf[p][lane32][17] = l[r * 2 + 1];
        }
        __syncthreads();
        {
            const int c = t & 255;
            const int qq = t >> 8;           // 0..1
            const int og = c & 7, od = c >> 3;
            const int ogd = og * 4 + (od >> 3), odd = od & 7;
            float s = 0.f, ls = 0.f;
#pragma unroll
            for (int pp = 0; pp < 16; ++pp) {
                s  += accbuf[pp][ogd][qq * 8 + odd];
                ls += accbuf[pp][og * 4][16 + qq];
            }
            out[((size_t)(b * LL) + q0 + r * 2 + qq) * 256 + c] = s / ls;
        }
        __syncthreads();
    }
}

// ---------------------------------------------------------------------------
extern "C" void kernel_launch(void* const* d_in, const int* in_sizes, int n_in,
                              void* d_out, int out_size, void* d_ws, size_t ws_size,
                              hipStream_t stream) {
    (void)in_sizes; (void)n_in; (void)out_size; (void)ws_size;
    const float* x     = (const float*)d_in[0];
    const float* Wq    = (const float*)d_in[1];
    const float* Wk    = (const float*)d_in[2];
    const float* Wv    = (const float*)d_in[3];
    const float* w_mlp = (const float*)d_in[4];
    const float* b_mlp = (const float*)d_in[5];
    float* outp = (float*)d_out;
    float* Y    = (float*)d_ws;          // Q | K | Vt : 3 * 2048*256 fp32 = 6 MB

    qkv_gemm<<<dim3(12, 64), 128, 0, stream>>>(x, Wq, Wk, Wv, Y);
    attn_fused<<<dim3(256), 512, 0, stream>>>(Y, w_mlp, b_mlp, outp);
}

// Round 3
// 128.818 us; speedup vs baseline: 1.0861x; 1.0110x over previous
//
#include <hip/hip_runtime.h>

typedef float f32x2 __attribute__((ext_vector_type(2)));
typedef float f32x4 __attribute__((ext_vector_type(4)));
typedef short bf16x8 __attribute__((ext_vector_type(8)));

#define LL 512
#define M_ROWS 2048            // 4 * 512
#define KC 768                 // split-K: [hi|hi|lo] x [hi|lo|hi]

__device__ __forceinline__ float quad_swap1(float x) {
    return __int_as_float(__builtin_amdgcn_mov_dpp(__float_as_int(x), 0xB1, 0xF, 0xF, true));
}
__device__ __forceinline__ float quad_swap2(float x) {
    return __int_as_float(__builtin_amdgcn_mov_dpp(__float_as_int(x), 0x4E, 0xF, 0xF, true));
}

__device__ __forceinline__ unsigned short bf16_rtne(float x) {
    unsigned u = __float_as_uint(x);
    return (unsigned short)((u + 0x7fffu + ((u >> 16) & 1u)) >> 16);
}
__device__ __forceinline__ float bf16_to_f(unsigned short h) {
    return __uint_as_float((unsigned)h << 16);
}

// ---------------------------------------------------------------------------
// Kernel 0: split fp32 -> bf16 (hi, lo) concatenated along K.
// Xcat[m][0:256]=hi  [256:512]=hi  [512:768]=lo
// Wcat[n][0:256]=hi  [256:512]=lo  [512:768]=hi   (pairs: hh + h*l + l*h)
// Wcat rows for mat 2 are permuted so the GEMM writes Vt directly.
// grid 2816 blocks x 64 thr: one source row each.
// ---------------------------------------------------------------------------
__global__ __launch_bounds__(64) void split_bf16(
    const float* __restrict__ X, const float* __restrict__ Wq,
    const float* __restrict__ Wk, const float* __restrict__ Wv,
    unsigned short* __restrict__ Xc, unsigned short* __restrict__ Wc)
{
    const int row = blockIdx.x;
    const int t = threadIdx.x;
    const float* src;
    unsigned short* hi1; unsigned short* hi2; unsigned short* lo1;
    if (row < M_ROWS) {
        src = X + (size_t)row * 256;
        hi1 = Xc + (size_t)row * KC;
        hi2 = hi1 + 256;
        lo1 = hi1 + 512;
    } else {
        const int n = row - M_ROWS;          // 0..767
        const int mat = n >> 8, c = n & 255;
        const int srow = (mat == 2) ? (((c & 31) << 3) | (c >> 5)) : c;
        src = (mat == 0 ? Wq : (mat == 1 ? Wk : Wv)) + (size_t)srow * 256;
        hi1 = Wc + (size_t)n * KC;
        lo1 = hi1 + 256;
        hi2 = hi1 + 512;
    }
    const f32x4 v = *(const f32x4*)(src + t * 4);
    ushort4 h, l;
    h.x = bf16_rtne(v.x); h.y = bf16_rtne(v.y); h.z = bf16_rtne(v.z); h.w = bf16_rtne(v.w);
    l.x = bf16_rtne(v.x - bf16_to_f(h.x));
    l.y = bf16_rtne(v.y - bf16_to_f(h.y));
    l.z = bf16_rtne(v.z - bf16_to_f(h.z));
    l.w = bf16_rtne(v.w - bf16_to_f(h.w));
    *(ushort4*)(hi1 + t * 4) = h;
    *(ushort4*)(hi2 + t * 4) = h;
    *(ushort4*)(lo1 + t * 4) = l;
}

// ---------------------------------------------------------------------------
// Kernel 1: Y = Xcat @ Wcat.T via bf16 MFMA, fp32 accumulate.
// grid 384 = 32 m-tiles x 12 n-tiles, 64 threads (1 wave), 64x64 wave tile,
// 4x4 grid of 16x16x32 MFMAs, no LDS (frags straight from L2).
// ---------------------------------------------------------------------------
__global__ __launch_bounds__(64) void qkv_mfma(
    const unsigned short* __restrict__ Xc, const unsigned short* __restrict__ Wc,
    float* __restrict__ Y)
{
    const int bid = blockIdx.x;
    const int m0 = (bid & 31) * 64;
    const int n0 = (bid >> 5) * 64;
    const int l = threadIdx.x;
    const int lr = l & 15;
    const int lk = (l >> 4) * 8;

    size_t aoff[4], boff[4];
#pragma unroll
    for (int i = 0; i < 4; ++i) {
        aoff[i] = (size_t)(m0 + i * 16 + lr) * KC + lk;
        boff[i] = (size_t)(n0 + i * 16 + lr) * KC + lk;
    }

    f32x4 acc[4][4];
#pragma unroll
    for (int i = 0; i < 4; ++i)
#pragma unroll
        for (int j = 0; j < 4; ++j) acc[i][j] = (f32x4){0.f, 0.f, 0.f, 0.f};

    bf16x8 A0[4], B0[4], A1[4], B1[4];
#pragma unroll
    for (int i = 0; i < 4; ++i) {
        A0[i] = *(const bf16x8*)(Xc + aoff[i]);
        B0[i] = *(const bf16x8*)(Wc + boff[i]);
    }

#pragma unroll 1
    for (int it = 0; it < 24; it += 2) {
        const int ks1 = (it + 1) * 32;
#pragma unroll
        for (int i = 0; i < 4; ++i) {
            A1[i] = *(const bf16x8*)(Xc + aoff[i] + ks1);
            B1[i] = *(const bf16x8*)(Wc + boff[i] + ks1);
        }
#pragma unroll
        for (int ai = 0; ai < 4; ++ai)
#pragma unroll
            for (int bi = 0; bi < 4; ++bi)
                acc[ai][bi] = __builtin_amdgcn_mfma_f32_16x16x32_bf16(
                    A0[ai], B0[bi], acc[ai][bi], 0, 0, 0);
        if (it + 2 < 24) {
            const int ks2 = (it + 2) * 32;
#pragma unroll
            for (int i = 0; i < 4; ++i) {
                A0[i] = *(const bf16x8*)(Xc + aoff[i] + ks2);
                B0[i] = *(const bf16x8*)(Wc + boff[i] + ks2);
            }
        }
#pragma unroll
        for (int ai = 0; ai < 4; ++ai)
#pragma unroll
            for (int bi = 0; bi < 4; ++bi)
                acc[ai][bi] = __builtin_amdgcn_mfma_f32_16x16x32_bf16(
                    A1[ai], B1[bi], acc[ai][bi], 0, 0, 0);
    }

    // C/D layout: col = lane&15, row = (lane>>4)*4 + reg
    const int mat = n0 >> 8;
    float* Yb = Y + (size_t)mat * M_ROWS * 256;
#pragma unroll
    for (int ai = 0; ai < 4; ++ai)
#pragma unroll
        for (int bi = 0; bi < 4; ++bi) {
            const int col = (n0 & 255) + bi * 16 + lr;
#pragma unroll
            for (int r = 0; r < 4; ++r) {
                const int row = m0 + ai * 16 + (l >> 4) * 4 + r;
                Yb[(size_t)row * 256 + col] = acc[ai][bi][r];
            }
        }
}

// ---------------------------------------------------------------------------
// Kernel 2: fused grouped-MLP attention (R2 main loop, spill-free epilogue).
// grid 256 = 4 batches x 64 q-tiles (8 q rows), 256 threads.
// thread = (dh = t&3: 8-float d-slice, g = (t>>2)&7, p = t>>5: k-phase of 8).
// ---------------------------------------------------------------------------
#define ACC_S 73
__global__ __launch_bounds__(256, 1) void attn_fused(
    const float* __restrict__ Y,
    const float* __restrict__ w_mlp, const float* __restrict__ b_mlp,
    float* __restrict__ out)
{
    const float* Qm = Y;
    const float* Km = Y + (size_t)M_ROWS * 256;
    const float* Vt = Y + (size_t)2 * M_ROWS * 256;

    const int bid = blockIdx.x;
    const int b = bid & 3;
    const int q0 = (bid >> 2) * 8;

    const int t = threadIdx.x;
    const int dh = t & 3;
    const int g = (t >> 2) & 7;
    const int p = t >> 5;                    // 0..7

    __shared__ float accbuf[8][32][ACC_S];   // ~74.8 KB
    __shared__ float ltot[8][8];             // [g][q]

    const int doff = g * 32 + dh * 8;
    const float bias = b_mlp[0];

    f32x2 w2[4];
    {
        f32x4 wa = *(const f32x4*)(w_mlp + dh * 8);
        f32x4 wb = *(const f32x4*)(w_mlp + dh * 8 + 4);
        w2[0] = __builtin_shufflevector(wa, wa, 0, 1);
        w2[1] = __builtin_shufflevector(wa, wa, 2, 3);
        w2[2] = __builtin_shufflevector(wb, wb, 0, 1);
        w2[3] = __builtin_shufflevector(wb, wb, 2, 3);
    }

    f32x2 qr2[8][4];
#pragma unroll
    for (int q = 0; q < 8; ++q) {
        const float* qp = Qm + ((size_t)(b * LL) + q0 + q) * 256 + doff;
        f32x4 qa = *(const f32x4*)qp;
        f32x4 qb = *(const f32x4*)(qp + 4);
        qr2[q][0] = __builtin_shufflevector(qa, qa, 0, 1);
        qr2[q][1] = __builtin_shufflevector(qa, qa, 2, 3);
        qr2[q][2] = __builtin_shufflevector(qb, qb, 0, 1);
        qr2[q][3] = __builtin_shufflevector(qb, qb, 2, 3);
    }

    f32x2 acc2[8][4];
#pragma unroll
    for (int q = 0; q < 8; ++q)
#pragma unroll
        for (int j = 0; j < 4; ++j) acc2[q][j] = (f32x2){0.f, 0.f};
    float l[8] = {0.f, 0.f, 0.f, 0.f, 0.f, 0.f, 0.f, 0.f};

    const float* kptr = Km + ((size_t)(b * LL) + p) * 256 + doff;
    const float* vptr = Vt + ((size_t)(b * LL) + p) * 256 + doff;

    auto compute = [&](f32x4 ka, f32x4 kb, f32x4 va, f32x4 vb) {
        f32x2 k2[4] = {__builtin_shufflevector(ka, ka, 0, 1),
                       __builtin_shufflevector(ka, ka, 2, 3),
                       __builtin_shufflevector(kb, kb, 0, 1),
                       __builtin_shufflevector(kb, kb, 2, 3)};
        f32x2 v2[4] = {__builtin_shufflevector(va, va, 0, 1),
                       __builtin_shufflevector(va, va, 2, 3),
                       __builtin_shufflevector(vb, vb, 0, 1),
                       __builtin_shufflevector(vb, vb, 2, 3)};
        const f32x2 z2 = {0.f, 0.f};
#pragma unroll
        for (int q = 0; q < 8; ++q) {
            f32x2 s2 = z2;
#pragma unroll
            for (int j = 0; j < 4; ++j) {
                f32x2 d2 = qr2[q][j] - k2[j];
                f32x2 r2 = __builtin_elementwise_max(d2, z2);
                s2 += w2[j] * r2;
            }
            float s = s2.x + s2.y;
            s += quad_swap1(s);
            s += quad_swap2(s);
            s = fmaxf(s + bias, 0.f);
            const float e = __expf(s);
            l[q] += e;
            const f32x2 e2 = {e, e};
#pragma unroll
            for (int j = 0; j < 4; ++j) acc2[q][j] += e2 * v2[j];
        }
    };

    f32x4 ka = *(const f32x4*)kptr, kb = *(const f32x4*)(kptr + 4);
    f32x4 va = *(const f32x4*)vptr, vb = *(const f32x4*)(vptr + 4);
#pragma unroll 1
    for (int i = 0; i < 63; ++i) {
        kptr += 8 * 256; vptr += 8 * 256;
        f32x4 ka2 = *(const f32x4*)kptr, kb2 = *(const f32x4*)(kptr + 4);
        f32x4 va2 = *(const f32x4*)vptr, vb2 = *(const f32x4*)(vptr + 4);
        compute(ka, kb, va, vb);
        ka = ka2; kb = kb2; va = va2; vb = vb2;
    }
    compute(ka, kb, va, vb);

    // ---- epilogue: single-shot, all indices compile-time ----
    {
        float* rowp = &accbuf[p][g * 4 + dh][0];
#pragma unroll
        for (int q = 0; q < 8; ++q)
#pragma unroll
            for (int j = 0; j < 4; ++j)
                *(f32x2*)(rowp + q * 8 + j * 2) = acc2[q][j];
        if (dh == 0) {
            float* lp = &accbuf[p][g * 4][64];
#pragma unroll
            for (int q = 0; q < 8; ++q) lp[q] = l[q];
        }
    }
    __syncthreads();

    if (t < 64) {
        const int gg = t >> 3, qq = t & 7;
        float s = 0.f;
#pragma unroll
        for (int pp = 0; pp < 8; ++pp) s += accbuf[pp][gg * 4][64 + qq];
        ltot[gg][qq] = s;
    }
    __syncthreads();

    {
        const int q = t >> 5;                // 0..7
        const int dval = t & 31;             // within-group d
        const int dhh = dval >> 3, jj = dval & 7;
        float res[8];
#pragma unroll
        for (int gg = 0; gg < 8; ++gg) {
            float s = 0.f;
#pragma unroll
            for (int pp = 0; pp < 8; ++pp) s += accbuf[pp][gg * 4 + dhh][q * 8 + jj];
            res[gg] = s / ltot[gg][q];
        }
        float* op = out + ((size_t)(b * LL) + q0 + q) * 256 + dval * 8;
        *(f32x4*)op       = (f32x4){res[0], res[1], res[2], res[3]};
        *(f32x4*)(op + 4) = (f32x4){res[4], res[5], res[6], res[7]};
    }
}

// ---------------------------------------------------------------------------
extern "C" void kernel_launch(void* const* d_in, const int* in_sizes, int n_in,
                              void* d_out, int out_size, void* d_ws, size_t ws_size,
                              hipStream_t stream) {
    (void)in_sizes; (void)n_in; (void)out_size; (void)ws_size;
    const float* x     = (const float*)d_in[0];
    const float* Wq    = (const float*)d_in[1];
    const float* Wk    = (const float*)d_in[2];
    const float* Wv    = (const float*)d_in[3];
    const float* w_mlp = (const float*)d_in[4];
    const float* b_mlp = (const float*)d_in[5];
    float* outp = (float*)d_out;

    float* Y = (float*)d_ws;                                   // 6 MB
    unsigned short* Xc = (unsigned short*)((char*)d_ws + (size_t)6291456);      // 3 MB
    unsigned short* Wc = (unsigned short*)((char*)d_ws + (size_t)6291456 + 3145728); // 1.125 MB

    split_bf16<<<dim3(M_ROWS + 768), 64, 0, stream>>>(x, Wq, Wk, Wv, Xc, Wc);
    qkv_mfma<<<dim3(384), 64, 0, stream>>>(Xc, Wc, Y);
    attn_fused<<<dim3(256), 256, 0, stream>>>(Y, w_mlp, b_mlp, outp);
}

// Round 4
// 125.747 us; speedup vs baseline: 1.1126x; 1.0244x over previous
//
#include <hip/hip_runtime.h>

typedef float f32x2 __attribute__((ext_vector_type(2)));
typedef float f32x4 __attribute__((ext_vector_type(4)));
typedef short bf16x8 __attribute__((ext_vector_type(8)));

#define LL 512
#define M_ROWS 2048            // 4 * 512
#define KC 768                 // split-K: [hi|hi|lo] x [hi|lo|hi]

#if __has_builtin(__builtin_amdgcn_exp2f)
#define EXP2F __builtin_amdgcn_exp2f
#else
#define EXP2F exp2f
#endif
#define LOG2E 1.44269504088896340736f

__device__ __forceinline__ float quad_swap1(float x) {
    return __int_as_float(__builtin_amdgcn_mov_dpp(__float_as_int(x), 0xB1, 0xF, 0xF, true));
}
__device__ __forceinline__ float quad_swap2(float x) {
    return __int_as_float(__builtin_amdgcn_mov_dpp(__float_as_int(x), 0x4E, 0xF, 0xF, true));
}

__device__ __forceinline__ unsigned short bf16_rtne(float x) {
    unsigned u = __float_as_uint(x);
    return (unsigned short)((u + 0x7fffu + ((u >> 16) & 1u)) >> 16);
}
__device__ __forceinline__ float bf16_to_f(unsigned short h) {
    return __uint_as_float((unsigned)h << 16);
}

// ---------------------------------------------------------------------------
// Kernel 0: split fp32 -> bf16 (hi, lo) concatenated along K. (unchanged)
// ---------------------------------------------------------------------------
__global__ __launch_bounds__(64) void split_bf16(
    const float* __restrict__ X, const float* __restrict__ Wq,
    const float* __restrict__ Wk, const float* __restrict__ Wv,
    unsigned short* __restrict__ Xc, unsigned short* __restrict__ Wc)
{
    const int row = blockIdx.x;
    const int t = threadIdx.x;
    const float* src;
    unsigned short* hi1; unsigned short* hi2; unsigned short* lo1;
    if (row < M_ROWS) {
        src = X + (size_t)row * 256;
        hi1 = Xc + (size_t)row * KC;
        hi2 = hi1 + 256;
        lo1 = hi1 + 512;
    } else {
        const int n = row - M_ROWS;          // 0..767
        const int mat = n >> 8, c = n & 255;
        const int srow = (mat == 2) ? (((c & 31) << 3) | (c >> 5)) : c;
        src = (mat == 0 ? Wq : (mat == 1 ? Wk : Wv)) + (size_t)srow * 256;
        hi1 = Wc + (size_t)n * KC;
        lo1 = hi1 + 256;
        hi2 = hi1 + 512;
    }
    const f32x4 v = *(const f32x4*)(src + t * 4);
    ushort4 h, l;
    h.x = bf16_rtne(v.x); h.y = bf16_rtne(v.y); h.z = bf16_rtne(v.z); h.w = bf16_rtne(v.w);
    l.x = bf16_rtne(v.x - bf16_to_f(h.x));
    l.y = bf16_rtne(v.y - bf16_to_f(h.y));
    l.z = bf16_rtne(v.z - bf16_to_f(h.z));
    l.w = bf16_rtne(v.w - bf16_to_f(h.w));
    *(ushort4*)(hi1 + t * 4) = h;
    *(ushort4*)(hi2 + t * 4) = h;
    *(ushort4*)(lo1 + t * 4) = l;
}

// ---------------------------------------------------------------------------
// Kernel 1: Y = Xcat @ Wcat.T via bf16 MFMA. (unchanged)
// ---------------------------------------------------------------------------
__global__ __launch_bounds__(64) void qkv_mfma(
    const unsigned short* __restrict__ Xc, const unsigned short* __restrict__ Wc,
    float* __restrict__ Y)
{
    const int bid = blockIdx.x;
    const int m0 = (bid & 31) * 64;
    const int n0 = (bid >> 5) * 64;
    const int l = threadIdx.x;
    const int lr = l & 15;
    const int lk = (l >> 4) * 8;

    size_t aoff[4], boff[4];
#pragma unroll
    for (int i = 0; i < 4; ++i) {
        aoff[i] = (size_t)(m0 + i * 16 + lr) * KC + lk;
        boff[i] = (size_t)(n0 + i * 16 + lr) * KC + lk;
    }

    f32x4 acc[4][4];
#pragma unroll
    for (int i = 0; i < 4; ++i)
#pragma unroll
        for (int j = 0; j < 4; ++j) acc[i][j] = (f32x4){0.f, 0.f, 0.f, 0.f};

    bf16x8 A0[4], B0[4], A1[4], B1[4];
#pragma unroll
    for (int i = 0; i < 4; ++i) {
        A0[i] = *(const bf16x8*)(Xc + aoff[i]);
        B0[i] = *(const bf16x8*)(Wc + boff[i]);
    }

#pragma unroll 1
    for (int it = 0; it < 24; it += 2) {
        const int ks1 = (it + 1) * 32;
#pragma unroll
        for (int i = 0; i < 4; ++i) {
            A1[i] = *(const bf16x8*)(Xc + aoff[i] + ks1);
            B1[i] = *(const bf16x8*)(Wc + boff[i] + ks1);
        }
#pragma unroll
        for (int ai = 0; ai < 4; ++ai)
#pragma unroll
            for (int bi = 0; bi < 4; ++bi)
                acc[ai][bi] = __builtin_amdgcn_mfma_f32_16x16x32_bf16(
                    A0[ai], B0[bi], acc[ai][bi], 0, 0, 0);
        if (it + 2 < 24) {
            const int ks2 = (it + 2) * 32;
#pragma unroll
            for (int i = 0; i < 4; ++i) {
                A0[i] = *(const bf16x8*)(Xc + aoff[i] + ks2);
                B0[i] = *(const bf16x8*)(Wc + boff[i] + ks2);
            }
        }
#pragma unroll
        for (int ai = 0; ai < 4; ++ai)
#pragma unroll
            for (int bi = 0; bi < 4; ++bi)
                acc[ai][bi] = __builtin_amdgcn_mfma_f32_16x16x32_bf16(
                    A1[ai], B1[bi], acc[ai][bi], 0, 0, 0);
    }

    const int mat = n0 >> 8;
    float* Yb = Y + (size_t)mat * M_ROWS * 256;
#pragma unroll
    for (int ai = 0; ai < 4; ++ai)
#pragma unroll
        for (int bi = 0; bi < 4; ++bi) {
            const int col = (n0 & 255) + bi * 16 + lr;
#pragma unroll
            for (int r = 0; r < 4; ++r) {
                const int row = m0 + ai * 16 + (l >> 4) * 4 + r;
                Yb[(size_t)row * 256 + col] = acc[ai][bi][r];
            }
        }
}

// ---------------------------------------------------------------------------
// Kernel 2: fused grouped-MLP attention.
// grid 256 = 4 batches x 64 q-tiles (8 q rows), 512 threads -> 2 waves/SIMD.
// thread = (dh = t&3: 8-float d-slice, g = (t>>2)&7, p = t>>5: k-phase 0..15).
// Main loop LDS-free; w/bias pre-scaled by log2(e), bias seeded as bias/4.
// ---------------------------------------------------------------------------
__global__ __launch_bounds__(512, 2) void attn_fused(
    const float* __restrict__ Y,
    const float* __restrict__ w_mlp, const float* __restrict__ b_mlp,
    float* __restrict__ out)
{
    const float* Qm = Y;
    const float* Km = Y + (size_t)M_ROWS * 256;
    const float* Vt = Y + (size_t)2 * M_ROWS * 256;

    const int bid = blockIdx.x;
    const int b = bid & 3;
    const int q0 = (bid >> 2) * 8;

    const int t = threadIdx.x;
    const int dh = t & 3;
    const int p = t >> 5;                    // 0..15
    const int lane32 = t & 31;               // g*4 + dh
    const int g = lane32 >> 2;

    __shared__ float accbuf[16][32][37];     // 75776 B

    const int doff = g * 32 + dh * 8;
    const float bias4 = b_mlp[0] * (LOG2E * 0.25f);

    f32x2 w2[4];
    {
        f32x4 wa = *(const f32x4*)(w_mlp + dh * 8);
        f32x4 wb = *(const f32x4*)(w_mlp + dh * 8 + 4);
        wa *= LOG2E; wb *= LOG2E;
        w2[0] = __builtin_shufflevector(wa, wa, 0, 1);
        w2[1] = __builtin_shufflevector(wa, wa, 2, 3);
        w2[2] = __builtin_shufflevector(wb, wb, 0, 1);
        w2[3] = __builtin_shufflevector(wb, wb, 2, 3);
    }

    f32x2 qr2[8][4];
#pragma unroll
    for (int q = 0; q < 8; ++q) {
        const float* qp = Qm + ((size_t)(b * LL) + q0 + q) * 256 + doff;
        f32x4 qa = *(const f32x4*)qp;
        f32x4 qb = *(const f32x4*)(qp + 4);
        qr2[q][0] = __builtin_shufflevector(qa, qa, 0, 1);
        qr2[q][1] = __builtin_shufflevector(qa, qa, 2, 3);
        qr2[q][2] = __builtin_shufflevector(qb, qb, 0, 1);
        qr2[q][3] = __builtin_shufflevector(qb, qb, 2, 3);
    }

    f32x2 acc2[8][4];
#pragma unroll
    for (int q = 0; q < 8; ++q)
#pragma unroll
        for (int j = 0; j < 4; ++j) acc2[q][j] = (f32x2){0.f, 0.f};
    float l[8] = {0.f, 0.f, 0.f, 0.f, 0.f, 0.f, 0.f, 0.f};

    const float* kptr = Km + ((size_t)(b * LL) + p) * 256 + doff;
    const float* vptr = Vt + ((size_t)(b * LL) + p) * 256 + doff;

    auto compute = [&](f32x4 ka, f32x4 kb, f32x4 va, f32x4 vb) {
        f32x2 k2[4] = {__builtin_shufflevector(ka, ka, 0, 1),
                       __builtin_shufflevector(ka, ka, 2, 3),
                       __builtin_shufflevector(kb, kb, 0, 1),
                       __builtin_shufflevector(kb, kb, 2, 3)};
        f32x2 v2[4] = {__builtin_shufflevector(va, va, 0, 1),
                       __builtin_shufflevector(va, va, 2, 3),
                       __builtin_shufflevector(vb, vb, 0, 1),
                       __builtin_shufflevector(vb, vb, 2, 3)};
        const f32x2 z2 = {0.f, 0.f};
#pragma unroll
        for (int q = 0; q < 8; ++q) {
            f32x2 s2 = {bias4, 0.f};
#pragma unroll
            for (int j = 0; j < 4; ++j) {
                f32x2 d2 = qr2[q][j] - k2[j];
                f32x2 r2 = __builtin_elementwise_max(d2, z2);
                s2 += w2[j] * r2;
            }
            float s = s2.x + s2.y;
            s += quad_swap1(s);
            s += quad_swap2(s);
            s = fmaxf(s, 0.f);
            const float e = EXP2F(s);
            l[q] += e;
            const f32x2 e2 = {e, e};
#pragma unroll
            for (int j = 0; j < 4; ++j) acc2[q][j] += e2 * v2[j];
        }
    };

    f32x4 ka = *(const f32x4*)kptr, kb = *(const f32x4*)(kptr + 4);
    f32x4 va = *(const f32x4*)vptr, vb = *(const f32x4*)(vptr + 4);
#pragma unroll 1
    for (int i = 0; i < 31; ++i) {
        kptr += 16 * 256; vptr += 16 * 256;
        f32x4 ka2 = *(const f32x4*)kptr, kb2 = *(const f32x4*)(kptr + 4);
        f32x4 va2 = *(const f32x4*)vptr, vb2 = *(const f32x4*)(vptr + 4);
        compute(ka, kb, va, vb);
        ka = ka2; kb = kb2; va = va2; vb = vb2;
    }
    compute(ka, kb, va, vb);

    // ---- epilogue: 2 fully-unrolled rounds of 4 q, 16-phase LDS reduction ----
    const int c_o = t & 255;
    const int g_o = c_o & 7, d_o = c_o >> 3;
    const int rowb = g_o * 4 + (d_o >> 3);
    const int colb = d_o & 7;
    const int qsel = t >> 8;                 // 0..1

    // ---- round 0: q = 0..3 ----
    {
        float* rowp = &accbuf[p][lane32][0];
#pragma unroll
        for (int qq = 0; qq < 4; ++qq)
#pragma unroll
            for (int j = 0; j < 4; ++j)
                *(f32x2*)(rowp + qq * 8 + j * 2) = acc2[qq][j];
        if (dh == 0) {
#pragma unroll
            for (int qq = 0; qq < 4; ++qq) accbuf[p][lane32][32 + qq] = l[qq];
        }
    }
    __syncthreads();
#pragma unroll
    for (int h = 0; h < 2; ++h) {
        const int qh = qsel + 2 * h;
        float s = 0.f, ls = 0.f;
#pragma unroll
        for (int pp = 0; pp < 16; ++pp) {
            s  += accbuf[pp][rowb][qh * 8 + colb];
            ls += accbuf[pp][g_o * 4][32 + qh];
        }
        out[((size_t)(b * LL) + q0 + qh) * 256 + c_o] = s / ls;
    }
    __syncthreads();

    // ---- round 1: q = 4..7 ----
    {
        float* rowp = &accbuf[p][lane32][0];
#pragma unroll
        for (int qq = 0; qq < 4; ++qq)
#pragma unroll
            for (int j = 0; j < 4; ++j)
                *(f32x2*)(rowp + qq * 8 + j * 2) = acc2[4 + qq][j];
        if (dh == 0) {
#pragma unroll
            for (int qq = 0; qq < 4; ++qq) accbuf[p][lane32][32 + qq] = l[4 + qq];
        }
    }
    __syncthreads();
#pragma unroll
    for (int h = 0; h < 2; ++h) {
        const int qh = qsel + 2 * h;
        float s = 0.f, ls = 0.f;
#pragma unroll
        for (int pp = 0; pp < 16; ++pp) {
            s  += accbuf[pp][rowb][qh * 8 + colb];
            ls += accbuf[pp][g_o * 4][32 + qh];
        }
        out[((size_t)(b * LL) + q0 + 4 + qh) * 256 + c_o] = s / ls;
    }
}

// ---------------------------------------------------------------------------
extern "C" void kernel_launch(void* const* d_in, const int* in_sizes, int n_in,
                              void* d_out, int out_size, void* d_ws, size_t ws_size,
                              hipStream_t stream) {
    (void)in_sizes; (void)n_in; (void)out_size; (void)ws_size;
    const float* x     = (const float*)d_in[0];
    const float* Wq    = (const float*)d_in[1];
    const float* Wk    = (const float*)d_in[2];
    const float* Wv    = (const float*)d_in[3];
    const float* w_mlp = (const float*)d_in[4];
    const float* b_mlp = (const float*)d_in[5];
    float* outp = (float*)d_out;

    float* Y = (float*)d_ws;                                   // 6 MB
    unsigned short* Xc = (unsigned short*)((char*)d_ws + (size_t)6291456);      // 3 MB
    unsigned short* Wc = (unsigned short*)((char*)d_ws + (size_t)6291456 + 3145728); // 1.125 MB

    split_bf16<<<dim3(M_ROWS + 768), 64, 0, stream>>>(x, Wq, Wk, Wv, Xc, Wc);
    qkv_mfma<<<dim3(384), 64, 0, stream>>>(Xc, Wc, Y);
    attn_fused<<<dim3(256), 512, 0, stream>>>(Y, w_mlp, b_mlp, outp);
}

// Round 5
// 124.294 us; speedup vs baseline: 1.1256x; 1.0117x over previous
//
#include <hip/hip_runtime.h>

typedef float f32x2 __attribute__((ext_vector_type(2)));
typedef float f32x4 __attribute__((ext_vector_type(4)));
typedef short bf16x8 __attribute__((ext_vector_type(8)));

#define LL 512
#define M_ROWS 2048            // 4 * 512
#define KC 768                 // split-K: [hi|hi|lo] x [hi|lo|hi]

#if __has_builtin(__builtin_amdgcn_exp2f)
#define EXP2F __builtin_amdgcn_exp2f
#else
#define EXP2F exp2f
#endif
#define LOG2E 1.44269504088896340736f

__device__ __forceinline__ float quad_swap1(float x) {
    return __int_as_float(__builtin_amdgcn_mov_dpp(__float_as_int(x), 0xB1, 0xF, 0xF, true));
}
__device__ __forceinline__ float quad_swap2(float x) {
    return __int_as_float(__builtin_amdgcn_mov_dpp(__float_as_int(x), 0x4E, 0xF, 0xF, true));
}

__device__ __forceinline__ unsigned short bf16_rtne(float x) {
    unsigned u = __float_as_uint(x);
    return (unsigned short)((u + 0x7fffu + ((u >> 16) & 1u)) >> 16);
}
__device__ __forceinline__ float bf16_to_f(unsigned short h) {
    return __uint_as_float((unsigned)h << 16);
}

// ---------------------------------------------------------------------------
// Kernel 0: split fp32 -> bf16 (hi, lo) concatenated along K. (unchanged)
// ---------------------------------------------------------------------------
__global__ __launch_bounds__(64) void split_bf16(
    const float* __restrict__ X, const float* __restrict__ Wq,
    const float* __restrict__ Wk, const float* __restrict__ Wv,
    unsigned short* __restrict__ Xc, unsigned short* __restrict__ Wc)
{
    const int row = blockIdx.x;
    const int t = threadIdx.x;
    const float* src;
    unsigned short* hi1; unsigned short* hi2; unsigned short* lo1;
    if (row < M_ROWS) {
        src = X + (size_t)row * 256;
        hi1 = Xc + (size_t)row * KC;
        hi2 = hi1 + 256;
        lo1 = hi1 + 512;
    } else {
        const int n = row - M_ROWS;          // 0..767
        const int mat = n >> 8, c = n & 255;
        const int srow = (mat == 2) ? (((c & 31) << 3) | (c >> 5)) : c;
        src = (mat == 0 ? Wq : (mat == 1 ? Wk : Wv)) + (size_t)srow * 256;
        hi1 = Wc + (size_t)n * KC;
        lo1 = hi1 + 256;
        hi2 = hi1 + 512;
    }
    const f32x4 v = *(const f32x4*)(src + t * 4);
    ushort4 h, l;
    h.x = bf16_rtne(v.x); h.y = bf16_rtne(v.y); h.z = bf16_rtne(v.z); h.w = bf16_rtne(v.w);
    l.x = bf16_rtne(v.x - bf16_to_f(h.x));
    l.y = bf16_rtne(v.y - bf16_to_f(h.y));
    l.z = bf16_rtne(v.z - bf16_to_f(h.z));
    l.w = bf16_rtne(v.w - bf16_to_f(h.w));
    *(ushort4*)(hi1 + t * 4) = h;
    *(ushort4*)(hi2 + t * 4) = h;
    *(ushort4*)(lo1 + t * 4) = l;
}

// ---------------------------------------------------------------------------
// Kernel 1: Y = Xcat @ Wcat.T via bf16 MFMA. (unchanged)
// ---------------------------------------------------------------------------
__global__ __launch_bounds__(64) void qkv_mfma(
    const unsigned short* __restrict__ Xc, const unsigned short* __restrict__ Wc,
    float* __restrict__ Y)
{
    const int bid = blockIdx.x;
    const int m0 = (bid & 31) * 64;
    const int n0 = (bid >> 5) * 64;
    const int l = threadIdx.x;
    const int lr = l & 15;
    const int lk = (l >> 4) * 8;

    size_t aoff[4], boff[4];
#pragma unroll
    for (int i = 0; i < 4; ++i) {
        aoff[i] = (size_t)(m0 + i * 16 + lr) * KC + lk;
        boff[i] = (size_t)(n0 + i * 16 + lr) * KC + lk;
    }

    f32x4 acc[4][4];
#pragma unroll
    for (int i = 0; i < 4; ++i)
#pragma unroll
        for (int j = 0; j < 4; ++j) acc[i][j] = (f32x4){0.f, 0.f, 0.f, 0.f};

    bf16x8 A0[4], B0[4], A1[4], B1[4];
#pragma unroll
    for (int i = 0; i < 4; ++i) {
        A0[i] = *(const bf16x8*)(Xc + aoff[i]);
        B0[i] = *(const bf16x8*)(Wc + boff[i]);
    }

#pragma unroll 1
    for (int it = 0; it < 24; it += 2) {
        const int ks1 = (it + 1) * 32;
#pragma unroll
        for (int i = 0; i < 4; ++i) {
            A1[i] = *(const bf16x8*)(Xc + aoff[i] + ks1);
            B1[i] = *(const bf16x8*)(Wc + boff[i] + ks1);
        }
#pragma unroll
        for (int ai = 0; ai < 4; ++ai)
#pragma unroll
            for (int bi = 0; bi < 4; ++bi)
                acc[ai][bi] = __builtin_amdgcn_mfma_f32_16x16x32_bf16(
                    A0[ai], B0[bi], acc[ai][bi], 0, 0, 0);
        if (it + 2 < 24) {
            const int ks2 = (it + 2) * 32;
#pragma unroll
            for (int i = 0; i < 4; ++i) {
                A0[i] = *(const bf16x8*)(Xc + aoff[i] + ks2);
                B0[i] = *(const bf16x8*)(Wc + boff[i] + ks2);
            }
        }
#pragma unroll
        for (int ai = 0; ai < 4; ++ai)
#pragma unroll
            for (int bi = 0; bi < 4; ++bi)
                acc[ai][bi] = __builtin_amdgcn_mfma_f32_16x16x32_bf16(
                    A1[ai], B1[bi], acc[ai][bi], 0, 0, 0);
    }

    const int mat = n0 >> 8;
    float* Yb = Y + (size_t)mat * M_ROWS * 256;
#pragma unroll
    for (int ai = 0; ai < 4; ++ai)
#pragma unroll
        for (int bi = 0; bi < 4; ++bi) {
            const int col = (n0 & 255) + bi * 16 + lr;
#pragma unroll
            for (int r = 0; r < 4; ++r) {
                const int row = m0 + ai * 16 + (l >> 4) * 4 + r;
                Yb[(size_t)row * 256 + col] = acc[ai][bi][r];
            }
        }
}

// ---------------------------------------------------------------------------
// Kernel 2: fused grouped-MLP attention.
// grid 512 = 4 batches x 128 q-tiles (4 q rows), 512 threads
//   -> 2 blocks/CU (LDS 75.8 KB each), 4 waves/SIMD.
// thread = (dh = t&3: 8-float d-slice, g = (t>>2)&7, p = t>>5: k-phase 0..15).
// ---------------------------------------------------------------------------
__global__ __launch_bounds__(512, 4) void attn_fused(
    const float* __restrict__ Y,
    const float* __restrict__ w_mlp, const float* __restrict__ b_mlp,
    float* __restrict__ out)
{
    const float* Qm = Y;
    const float* Km = Y + (size_t)M_ROWS * 256;
    const float* Vt = Y + (size_t)2 * M_ROWS * 256;

    const int bid = blockIdx.x;
    const int b = bid & 3;
    const int q0 = (bid >> 2) * 4;

    const int t = threadIdx.x;
    const int dh = t & 3;
    const int p = t >> 5;                    // 0..15
    const int lane32 = t & 31;               // g*4 + dh
    const int g = lane32 >> 2;

    __shared__ float accbuf[16][32][37];     // 75776 B (rows: 4q*8 + l[4])

    const int doff = g * 32 + dh * 8;
    const float bias4 = b_mlp[0] * (LOG2E * 0.25f);

    f32x2 w2[4];
    {
        f32x4 wa = *(const f32x4*)(w_mlp + dh * 8);
        f32x4 wb = *(const f32x4*)(w_mlp + dh * 8 + 4);
        wa *= LOG2E; wb *= LOG2E;
        w2[0] = __builtin_shufflevector(wa, wa, 0, 1);
        w2[1] = __builtin_shufflevector(wa, wa, 2, 3);
        w2[2] = __builtin_shufflevector(wb, wb, 0, 1);
        w2[3] = __builtin_shufflevector(wb, wb, 2, 3);
    }

    f32x2 qr2[4][4];
#pragma unroll
    for (int q = 0; q < 4; ++q) {
        const float* qp = Qm + ((size_t)(b * LL) + q0 + q) * 256 + doff;
        f32x4 qa = *(const f32x4*)qp;
        f32x4 qb = *(const f32x4*)(qp + 4);
        qr2[q][0] = __builtin_shufflevector(qa, qa, 0, 1);
        qr2[q][1] = __builtin_shufflevector(qa, qa, 2, 3);
        qr2[q][2] = __builtin_shufflevector(qb, qb, 0, 1);
        qr2[q][3] = __builtin_shufflevector(qb, qb, 2, 3);
    }

    f32x2 acc2[4][4];
#pragma unroll
    for (int q = 0; q < 4; ++q)
#pragma unroll
        for (int j = 0; j < 4; ++j) acc2[q][j] = (f32x2){0.f, 0.f};
    float l[4] = {0.f, 0.f, 0.f, 0.f};

    const float* kptr = Km + ((size_t)(b * LL) + p) * 256 + doff;
    const float* vptr = Vt + ((size_t)(b * LL) + p) * 256 + doff;

    auto compute = [&](f32x4 ka, f32x4 kb, f32x4 va, f32x4 vb) {
        f32x2 k2[4] = {__builtin_shufflevector(ka, ka, 0, 1),
                       __builtin_shufflevector(ka, ka, 2, 3),
                       __builtin_shufflevector(kb, kb, 0, 1),
                       __builtin_shufflevector(kb, kb, 2, 3)};
        f32x2 v2[4] = {__builtin_shufflevector(va, va, 0, 1),
                       __builtin_shufflevector(va, va, 2, 3),
                       __builtin_shufflevector(vb, vb, 0, 1),
                       __builtin_shufflevector(vb, vb, 2, 3)};
        const f32x2 z2 = {0.f, 0.f};
#pragma unroll
        for (int q = 0; q < 4; ++q) {
            f32x2 s2 = {bias4, 0.f};
#pragma unroll
            for (int j = 0; j < 4; ++j) {
                f32x2 d2 = qr2[q][j] - k2[j];
                f32x2 r2 = __builtin_elementwise_max(d2, z2);
                s2 += w2[j] * r2;
            }
            float s = s2.x + s2.y;
            s += quad_swap1(s);
            s += quad_swap2(s);
            s = fmaxf(s, 0.f);
            const float e = EXP2F(s);
            l[q] += e;
            const f32x2 e2 = {e, e};
#pragma unroll
            for (int j = 0; j < 4; ++j) acc2[q][j] += e2 * v2[j];
        }
    };

    f32x4 ka = *(const f32x4*)kptr, kb = *(const f32x4*)(kptr + 4);
    f32x4 va = *(const f32x4*)vptr, vb = *(const f32x4*)(vptr + 4);
#pragma unroll 1
    for (int i = 0; i < 31; ++i) {
        kptr += 16 * 256; vptr += 16 * 256;
        f32x4 ka2 = *(const f32x4*)kptr, kb2 = *(const f32x4*)(kptr + 4);
        f32x4 va2 = *(const f32x4*)vptr, vb2 = *(const f32x4*)(vptr + 4);
        compute(ka, kb, va, vb);
        ka = ka2; kb = kb2; va = va2; vb = vb2;
    }
    compute(ka, kb, va, vb);

    // ---- epilogue: store 4 q + l, 16-phase LDS reduction, 2 outputs/thread --
    {
        float* rowp = &accbuf[p][lane32][0];
#pragma unroll
        for (int qq = 0; qq < 4; ++qq)
#pragma unroll
            for (int j = 0; j < 4; ++j)
                *(f32x2*)(rowp + qq * 8 + j * 2) = acc2[qq][j];
        if (dh == 0) {
#pragma unroll
            for (int qq = 0; qq < 4; ++qq) accbuf[p][lane32][32 + qq] = l[qq];
        }
    }
    __syncthreads();

    const int c_o = t & 255;
    const int g_o = c_o & 7, d_o = c_o >> 3;
    const int rowb = g_o * 4 + (d_o >> 3);
    const int colb = d_o & 7;
    const int qsel = t >> 8;                 // 0..1
#pragma unroll
    for (int h = 0; h < 2; ++h) {
        const int qh = qsel + 2 * h;         // 0..3
        float s = 0.f, ls = 0.f;
#pragma unroll
        for (int pp = 0; pp < 16; ++pp) {
            s  += accbuf[pp][rowb][qh * 8 + colb];
            ls += accbuf[pp][g_o * 4][32 + qh];
        }
        out[((size_t)(b * LL) + q0 + qh) * 256 + c_o] = s / ls;
    }
}

// ---------------------------------------------------------------------------
extern "C" void kernel_launch(void* const* d_in, const int* in_sizes, int n_in,
                              void* d_out, int out_size, void* d_ws, size_t ws_size,
                              hipStream_t stream) {
    (void)in_sizes; (void)n_in; (void)out_size; (void)ws_size;
    const float* x     = (const float*)d_in[0];
    const float* Wq    = (const float*)d_in[1];
    const float* Wk    = (const float*)d_in[2];
    const float* Wv    = (const float*)d_in[3];
    const float* w_mlp = (const float*)d_in[4];
    const float* b_mlp = (const float*)d_in[5];
    float* outp = (float*)d_out;

    float* Y = (float*)d_ws;                                   // 6 MB
    unsigned short* Xc = (unsigned short*)((char*)d_ws + (size_t)6291456);      // 3 MB
    unsigned short* Wc = (unsigned short*)((char*)d_ws + (size_t)6291456 + 3145728); // 1.125 MB

    split_bf16<<<dim3(M_ROWS + 768), 64, 0, stream>>>(x, Wq, Wk, Wv, Xc, Wc);
    qkv_mfma<<<dim3(384), 64, 0, stream>>>(Xc, Wc, Y);
    attn_fused<<<dim3(512), 512, 0, stream>>>(Y, w_mlp, b_mlp, outp);
}